// Round 4
// baseline (405.564 us; speedup 1.0000x reference)
//
#include <hip/hip_runtime.h>
#include <cstdint>
#include <cstddef>

#define EPS_LN 1e-5f

typedef short bf16x8 __attribute__((ext_vector_type(8)));
typedef float f32x4 __attribute__((ext_vector_type(4)));
typedef unsigned int u32_gl __attribute__((address_space(1)));
typedef unsigned int u32_ld __attribute__((address_space(3)));

__device__ __forceinline__ unsigned short f2bf(float f) {
  union { float f; unsigned u; } v; v.f = f;
  unsigned r = v.u + 0x7fffu + ((v.u >> 16) & 1u);
  return (unsigned short)(r >> 16);
}

// 256-thread block sum (4 waves of 64)
__device__ __forceinline__ float block_sum256(float v, float* red) {
  for (int m = 32; m > 0; m >>= 1) v += __shfl_xor(v, m, 64);
  const int lane = threadIdx.x & 63, w = threadIdx.x >> 6;
  if (lane == 0) red[w] = v;
  __syncthreads();
  float r = red[0] + red[1] + red[2] + red[3];
  __syncthreads();
  return r;
}

// ---------- fused setup: w6 softmax + init H1pre/Ys/bias1 ----------
__global__ __launch_bounds__(256) void setup_small(
    const float* __restrict__ aw,
    const float* __restrict__ mb1, const float* __restrict__ nb1, const float* __restrict__ rb1,
    const float* __restrict__ mb2, const float* __restrict__ nb2, const float* __restrict__ rb2,
    const float* __restrict__ ib1,
    float* __restrict__ w, float* __restrict__ H1pre, float* __restrict__ Ys,
    float* __restrict__ bias1) {
  const int bi = blockIdx.x;
  if (bi == 0) {
    if (threadIdx.x == 0) {
      float m = aw[0];
      for (int i = 1; i < 6; ++i) m = fmaxf(m, aw[i]);
      float e[6], s = 0.f;
      for (int i = 0; i < 6; ++i) { e[i] = __expf(aw[i] - m); s += e[i]; }
      for (int i = 0; i < 6; ++i) w[i] = e[i] / s;
    }
    return;
  }
  if (bi <= 48) {  // H1pre: 12 x 1024 = b1
    const int idx = (bi - 1) * 256 + threadIdx.x;
    const int st = idx >> 12;  // row>>2 with row=idx>>10 -> idx>>12
    const float* b1 = st == 0 ? mb1 : st == 1 ? nb1 : rb1;
    H1pre[idx] = b1[idx & 1023];
    return;
  }
  if (bi <= 96) {  // Ys: 12 x 1024 = b2
    const int idx = (bi - 49) * 256 + threadIdx.x;
    const int st = idx >> 12;
    const float* b2 = st == 0 ? mb2 : st == 1 ? nb2 : rb2;
    Ys[idx] = b2[idx & 1023];
    return;
  }
  // bias1: 4 x 1024 = ib1
  const int idx = (bi - 97) * 256 + threadIdx.x;
  bias1[idx] = ib1[idx & 1023];
}

// ---------- split-K accumulate: H1pre[st*4+b][j] += sum_k state[b][k]*W1[k][j] ----------
__global__ __launch_bounds__(256) void state_h1_acc(
    const float* __restrict__ mem, const float* __restrict__ noi, const float* __restrict__ res,
    const float* __restrict__ mW1, const float* __restrict__ nW1, const float* __restrict__ rW1,
    float* __restrict__ H1pre) {
  // grid dim3(8, 10): y 0..7 = mem K-slices of 64; y=8 noi (K=64); y=9 res (K=32)
  const int chunk = blockIdx.x, ks = blockIdx.y;
  const int j = chunk * 128 + (threadIdx.x & 127);
  const int half = threadIdx.x >> 7;
  int st, k0, klen, sstride;
  const float* W1; const float* sp;
  if (ks < 8)       { st = 0; W1 = mW1; sp = mem; sstride = 512; k0 = ks * 64 + half * 32; klen = 32; }
  else if (ks == 8) { st = 1; W1 = nW1; sp = noi; sstride = 64;  k0 = half * 32;           klen = 32; }
  else              { st = 2; W1 = rW1; sp = res; sstride = 32;  k0 = half * 16;           klen = 16; }
  float a0 = 0.f, a1 = 0.f, a2 = 0.f, a3 = 0.f;
  const float* wp = W1 + (size_t)k0 * 1024 + j;
  for (int it = 0; it < klen; ++it) {
    const float wv = wp[(size_t)it * 1024];
    const int k = k0 + it;
    a0 += sp[k] * wv;
    a1 += sp[sstride + k] * wv;
    a2 += sp[2 * sstride + k] * wv;
    a3 += sp[3 * sstride + k] * wv;
  }
  __shared__ float part[4][128];
  const int jl = threadIdx.x & 127;
  if (half) { part[0][jl] = a0; part[1][jl] = a1; part[2][jl] = a2; part[3][jl] = a3; }
  __syncthreads();
  if (!half) {
    atomicAdd(&H1pre[(size_t)(st * 4 + 0) * 1024 + j], a0 + part[0][jl]);
    atomicAdd(&H1pre[(size_t)(st * 4 + 1) * 1024 + j], a1 + part[1][jl]);
    atomicAdd(&H1pre[(size_t)(st * 4 + 2) * 1024 + j], a2 + part[2][jl]);
    atomicAdd(&H1pre[(size_t)(st * 4 + 3) * 1024 + j], a3 + part[3][jl]);
  }
}

// ---------- split-K accumulate with inline silu on H1pre reads ----------
__global__ __launch_bounds__(256) void state_y_acc(
    const float* __restrict__ H1pre,
    const float* __restrict__ mW2, const float* __restrict__ nW2, const float* __restrict__ rW2,
    float* __restrict__ Ys) {
  // grid dim3(8, 16, 3): col chunk, K-slice of 64, stack
  const int chunk = blockIdx.x, ks = blockIdx.y, st = blockIdx.z;
  const float* W2 = st == 0 ? mW2 : st == 1 ? nW2 : rW2;
  const int j = chunk * 128 + (threadIdx.x & 127);
  const int half = threadIdx.x >> 7;
  const int k0 = ks * 64 + half * 32;
  const float* h1 = H1pre + (size_t)st * 4096;
  float a0 = 0.f, a1 = 0.f, a2 = 0.f, a3 = 0.f;
  const float* wp = W2 + (size_t)k0 * 1024 + j;
  for (int it = 0; it < 32; ++it) {
    const float wv = wp[(size_t)it * 1024];
    const int k = k0 + it;
    float h;
    h = h1[k];        a0 += (h / (1.f + __expf(-h))) * wv;
    h = h1[1024 + k]; a1 += (h / (1.f + __expf(-h))) * wv;
    h = h1[2048 + k]; a2 += (h / (1.f + __expf(-h))) * wv;
    h = h1[3072 + k]; a3 += (h / (1.f + __expf(-h))) * wv;
  }
  __shared__ float part[4][128];
  const int jl = threadIdx.x & 127;
  if (half) { part[0][jl] = a0; part[1][jl] = a1; part[2][jl] = a2; part[3][jl] = a3; }
  __syncthreads();
  if (!half) {
    atomicAdd(&Ys[(size_t)(st * 4 + 0) * 1024 + j], a0 + part[0][jl]);
    atomicAdd(&Ys[(size_t)(st * 4 + 1) * 1024 + j], a1 + part[1][jl]);
    atomicAdd(&Ys[(size_t)(st * 4 + 2) * 1024 + j], a2 + part[2][jl]);
    atomicAdd(&Ys[(size_t)(st * 4 + 3) * 1024 + j], a3 + part[3][jl]);
  }
}

// ---------- state MLP stage 3: mnrv[b][st*1024+j] = w[2+st] * LN(Ys) ----------
__global__ __launch_bounds__(256) void state_ln(
    const float* __restrict__ Ys,
    const float* __restrict__ mg, const float* __restrict__ mbe,
    const float* __restrict__ ng, const float* __restrict__ nbe,
    const float* __restrict__ rg, const float* __restrict__ rbe,
    const float* __restrict__ w, float* __restrict__ mnrv) {
  __shared__ float red[4];
  const int st = blockIdx.x >> 2, b = blockIdx.x & 3;
  const float* g  = st == 0 ? mg  : st == 1 ? ng  : rg;
  const float* be = st == 0 ? mbe : st == 1 ? nbe : rbe;
  const float* y = Ys + (size_t)blockIdx.x * 1024;
  const int j = threadIdx.x * 4;
  float4 yv4 = *(const float4*)(y + j);
  float yv[4] = { yv4.x, yv4.y, yv4.z, yv4.w };
  float s = yv[0] + yv[1] + yv[2] + yv[3];
  float ss = yv[0]*yv[0] + yv[1]*yv[1] + yv[2]*yv[2] + yv[3]*yv[3];
  s = block_sum256(s, red);
  ss = block_sum256(ss, red);
  const float mu = s * (1.f / 1024.f);
  const float rstd = rsqrtf(ss * (1.f / 1024.f) - mu * mu + EPS_LN);
  float4 g4 = *(const float4*)(g + j);
  float4 b4 = *(const float4*)(be + j);
  const float sc = w[2 + st];
  float* out = mnrv + (size_t)b * 3072 + st * 1024;
  out[j]     = ((yv[0] - mu) * rstd * g4.x + b4.x) * sc;
  out[j + 1] = ((yv[1] - mu) * rstd * g4.y + b4.y) * sc;
  out[j + 2] = ((yv[2] - mu) * rstd * g4.z + b4.z) * sc;
  out[j + 3] = ((yv[3] - mu) * rstd * g4.w + b4.w) * sc;
}

// ---------- per-batch GEMM-1 bias, split-K parallel + atomicAdd ----------
// bias1[b][j] += sum_g mnrv[b][g] * iW1[2048+g][j],  g in [0,3072)
__global__ __launch_bounds__(256) void bias1_kernel(
    const float* __restrict__ mnrv, const float* __restrict__ iW1,
    float* __restrict__ bias1) {
  // grid: dim3(8, 48) = (col chunk of 128, K-slice of 64)
  const int chunk = blockIdx.x, ks = blockIdx.y;
  const int j = chunk * 128 + (threadIdx.x & 127);
  const int half = threadIdx.x >> 7;
  const int g0 = ks * 64 + half * 32;
  float acc0 = 0.f, acc1 = 0.f, acc2 = 0.f, acc3 = 0.f;
  const float* wp = iW1 + (size_t)(2048 + g0) * 1024 + j;
  for (int it = 0; it < 32; ++it) {
    const int g = g0 + it;
    const float wv = wp[(size_t)it * 1024];
    acc0 += mnrv[g] * wv;
    acc1 += mnrv[3072 + g] * wv;
    acc2 += mnrv[6144 + g] * wv;
    acc3 += mnrv[9216 + g] * wv;
  }
  __shared__ float part[4][128];
  const int jl = threadIdx.x & 127;
  if (half) { part[0][jl] = acc0; part[1][jl] = acc1; part[2][jl] = acc2; part[3][jl] = acc3; }
  __syncthreads();
  if (!half) {
    atomicAdd(&bias1[j],        acc0 + part[0][jl]);
    atomicAdd(&bias1[1024 + j], acc1 + part[1][jl]);
    atomicAdd(&bias1[2048 + j], acc2 + part[2][jl]);
    atomicAdd(&bias1[3072 + j], acc3 + part[3][jl]);
  }
}

// ---------- build W1' transposed (N=1024 x K=4096, bf16), weight-combined ----------
__global__ __launch_bounds__(256) void build_w1t(
    const float* __restrict__ W1, const float* __restrict__ w,
    unsigned short* __restrict__ W1T) {
  __shared__ float tile[32][33];
  const int k0 = blockIdx.x * 32, n0 = blockIdx.y * 32;
  const int r = threadIdx.x >> 3;
  const int c = (threadIdx.x & 7) * 4;
  const int kk = k0 + r;
  float v[4];
  if (kk < 2048) {  // parts 0 (h, w0) and 1 (t, w1), source row == kk
    const float s = (kk < 1024) ? w[0] : w[1];
    float4 a = *(const float4*)(W1 + (size_t)kk * 1024 + n0 + c);
    v[0] = s * a.x; v[1] = s * a.y; v[2] = s * a.z; v[3] = s * a.w;
  } else if (kk < 3072) {  // x-block: w2*p2 + w3*p3 + w4*p4
    const float s2 = w[2], s3 = w[3], s4 = w[4];
    float4 a = *(const float4*)(W1 + (size_t)kk * 1024 + n0 + c);
    float4 bq = *(const float4*)(W1 + (size_t)(kk + 1024) * 1024 + n0 + c);
    float4 cq = *(const float4*)(W1 + (size_t)(kk + 2048) * 1024 + n0 + c);
    v[0] = s2 * a.x + s3 * bq.x + s4 * cq.x;
    v[1] = s2 * a.y + s3 * bq.y + s4 * cq.y;
    v[2] = s2 * a.z + s3 * bq.z + s4 * cq.z;
    v[3] = s2 * a.w + s3 * bq.w + s4 * cq.w;
  } else {  // part 5 (s, w5), source row kk+2048
    const float s = w[5];
    float4 a = *(const float4*)(W1 + (size_t)(kk + 2048) * 1024 + n0 + c);
    v[0] = s * a.x; v[1] = s * a.y; v[2] = s * a.z; v[3] = s * a.w;
  }
  tile[r][c] = v[0]; tile[r][c + 1] = v[1]; tile[r][c + 2] = v[2]; tile[r][c + 3] = v[3];
  __syncthreads();
  const int nl = threadIdx.x >> 3;
  const int k4 = (threadIdx.x & 7) * 4;
  ushort4 o;
  o.x = f2bf(tile[k4][nl]);     o.y = f2bf(tile[k4 + 1][nl]);
  o.z = f2bf(tile[k4 + 2][nl]); o.w = f2bf(tile[k4 + 3][nl]);
  *(ushort4*)(W1T + (size_t)(n0 + nl) * 4096 + k0 + k4) = o;
}

// ---------- W2 transposed to bf16 (1024 x 1024) ----------
__global__ __launch_bounds__(256) void build_w2t(
    const float* __restrict__ W2, unsigned short* __restrict__ W2T) {
  __shared__ float tile[32][33];
  const int k0 = blockIdx.x * 32, n0 = blockIdx.y * 32;
  const int r = threadIdx.x >> 3, c = (threadIdx.x & 7) * 4;
  float4 a = *(const float4*)(W2 + (size_t)(k0 + r) * 1024 + n0 + c);
  tile[r][c] = a.x; tile[r][c + 1] = a.y; tile[r][c + 2] = a.z; tile[r][c + 3] = a.w;
  __syncthreads();
  const int nl = threadIdx.x >> 3, k4 = (threadIdx.x & 7) * 4;
  ushort4 o;
  o.x = f2bf(tile[k4][nl]);     o.y = f2bf(tile[k4 + 1][nl]);
  o.z = f2bf(tile[k4 + 2][nl]); o.w = f2bf(tile[k4 + 3][nl]);
  *(ushort4*)(W2T + (size_t)(n0 + nl) * 1024 + k0 + k4) = o;
}

// ---------- per-token: build cat4 = [h, t, x, s] in bf16 (8192 x 4096) ----------
__global__ __launch_bounds__(256) void build_cat(
    const float* __restrict__ x,
    const int* __restrict__ pid_, const int* __restrict__ cid_,
    const int* __restrict__ tid_, const int* __restrict__ sid_,
    const float* __restrict__ pwg, const float* __restrict__ pwb,
    const float* __restrict__ cpg, const float* __restrict__ cpb,
    const float* __restrict__ tmg, const float* __restrict__ tmb,
    const float* __restrict__ msg, const float* __restrict__ msb,
    unsigned short* __restrict__ cat4) {
  __shared__ float red[4];
  const int row = blockIdx.x;
  const int j = threadIdx.x * 4;
  float4 xv4 = *(const float4*)(x + (size_t)row * 1024 + j);
  float xv[4] = { xv4.x, xv4.y, xv4.z, xv4.w };
  float s = xv[0] + xv[1] + xv[2] + xv[3];
  float ss = xv[0]*xv[0] + xv[1]*xv[1] + xv[2]*xv[2] + xv[3]*xv[3];
  s = block_sum256(s, red);
  ss = block_sum256(ss, red);
  const float mu = s * (1.f / 1024.f);
  const float rstd = rsqrtf(ss * (1.f / 1024.f) - mu * mu + EPS_LN);
  float xh[4];
  for (int q = 0; q < 4; ++q) xh[q] = (xv[q] - mu) * rstd;
  const int pid = pid_[row], cid = cid_[row], tmi = tid_[row], msi = sid_[row];
  unsigned short* crow = cat4 + (size_t)row * 4096;

  // h = LN(LN(x)*pwg+pwb) with cpg,cpb
  float4 g4 = *(const float4*)(pwg + (size_t)pid * 1024 + j);
  float4 b4 = *(const float4*)(pwb + (size_t)pid * 1024 + j);
  float h1[4];
  h1[0] = xh[0] * g4.x + b4.x; h1[1] = xh[1] * g4.y + b4.y;
  h1[2] = xh[2] * g4.z + b4.z; h1[3] = xh[3] * g4.w + b4.w;
  float s1 = h1[0] + h1[1] + h1[2] + h1[3];
  float ss1 = h1[0]*h1[0] + h1[1]*h1[1] + h1[2]*h1[2] + h1[3]*h1[3];
  s1 = block_sum256(s1, red);
  ss1 = block_sum256(ss1, red);
  const float mu1 = s1 * (1.f / 1024.f);
  const float rstd1 = rsqrtf(ss1 * (1.f / 1024.f) - mu1 * mu1 + EPS_LN);
  g4 = *(const float4*)(cpg + (size_t)cid * 1024 + j);
  b4 = *(const float4*)(cpb + (size_t)cid * 1024 + j);
  ushort4 o;
  o.x = f2bf((h1[0] - mu1) * rstd1 * g4.x + b4.x);
  o.y = f2bf((h1[1] - mu1) * rstd1 * g4.y + b4.y);
  o.z = f2bf((h1[2] - mu1) * rstd1 * g4.z + b4.z);
  o.w = f2bf((h1[3] - mu1) * rstd1 * g4.w + b4.w);
  *(ushort4*)(crow + j) = o;

  // t = LN(x) with tm
  g4 = *(const float4*)(tmg + (size_t)tmi * 1024 + j);
  b4 = *(const float4*)(tmb + (size_t)tmi * 1024 + j);
  o.x = f2bf(xh[0] * g4.x + b4.x); o.y = f2bf(xh[1] * g4.y + b4.y);
  o.z = f2bf(xh[2] * g4.z + b4.z); o.w = f2bf(xh[3] * g4.w + b4.w);
  *(ushort4*)(crow + 1024 + j) = o;

  // x raw
  o.x = f2bf(xv[0]); o.y = f2bf(xv[1]); o.z = f2bf(xv[2]); o.w = f2bf(xv[3]);
  *(ushort4*)(crow + 2048 + j) = o;

  // s = LN(x) with ms
  g4 = *(const float4*)(msg + (size_t)msi * 1024 + j);
  b4 = *(const float4*)(msb + (size_t)msi * 1024 + j);
  o.x = f2bf(xh[0] * g4.x + b4.x); o.y = f2bf(xh[1] * g4.y + b4.y);
  o.z = f2bf(xh[2] * g4.z + b4.z); o.w = f2bf(xh[3] * g4.w + b4.w);
  *(ushort4*)(crow + 3072 + j) = o;
}

// ---------- bf16 MFMA GEMM: C(M x 1024) = A(M x K) * BT(1024 x K)^T ----------
// BM=64 x BN=128 tile, 128 threads (2 waves, each 64x64 like m97).
// EPI 1: + bias1[row>>11][col], silu, store bf16.  EPI 2: + bias[col], store fp32.
template <int EPI>
__global__ __launch_bounds__(128, 4) void gemm_bt(
    const unsigned short* __restrict__ A, const unsigned short* __restrict__ BT,
    const float* __restrict__ bias, void* __restrict__ out, int K) {
  __shared__ unsigned short At[64 * 32];    // 4 KiB
  __shared__ unsigned short Bt[128 * 32];   // 8 KiB
  const int t = threadIdx.x;
  const int lane = t & 63;
  const int wc = t >> 6;                     // wave 0: cols 0-63, wave 1: cols 64-127
  const int quad = lane >> 4, l16 = lane & 15;
  const int bm = blockIdx.x, bn = blockIdx.y;
  const unsigned short* Ab = A + (size_t)bm * 64 * K;
  const unsigned short* Bb = BT + (size_t)bn * 128 * K;
  const int r0 = t >> 2, c0 = (t & 3) * 8;   // 128 threads stage 32 rows x 64B per instr
  f32x4 acc[4][4];
#pragma unroll
  for (int i = 0; i < 4; ++i)
#pragma unroll
    for (int jj = 0; jj < 4; ++jj) { f32x4 z = {0.f, 0.f, 0.f, 0.f}; acc[i][jj] = z; }

  for (int kt = 0; kt < K; kt += 32) {
    __builtin_amdgcn_global_load_lds(
        (const u32_gl*)(Ab + (size_t)r0 * K + kt + c0),
        (u32_ld*)(At + t * 8), 16, 0, 0);
    __builtin_amdgcn_global_load_lds(
        (const u32_gl*)(Ab + (size_t)(r0 + 32) * K + kt + c0),
        (u32_ld*)(At + (128 + t) * 8), 16, 0, 0);
    __builtin_amdgcn_global_load_lds(
        (const u32_gl*)(Bb + (size_t)r0 * K + kt + c0),
        (u32_ld*)(Bt + t * 8), 16, 0, 0);
    __builtin_amdgcn_global_load_lds(
        (const u32_gl*)(Bb + (size_t)(r0 + 32) * K + kt + c0),
        (u32_ld*)(Bt + (128 + t) * 8), 16, 0, 0);
    __builtin_amdgcn_global_load_lds(
        (const u32_gl*)(Bb + (size_t)(r0 + 64) * K + kt + c0),
        (u32_ld*)(Bt + (256 + t) * 8), 16, 0, 0);
    __builtin_amdgcn_global_load_lds(
        (const u32_gl*)(Bb + (size_t)(r0 + 96) * K + kt + c0),
        (u32_ld*)(Bt + (384 + t) * 8), 16, 0, 0);
    __syncthreads();
    bf16x8 aF[4], bF[4];
#pragma unroll
    for (int mi = 0; mi < 4; ++mi)
      aF[mi] = *(const bf16x8*)(At + (mi * 16 + l16) * 32 + quad * 8);
#pragma unroll
    for (int ni = 0; ni < 4; ++ni)
      bF[ni] = *(const bf16x8*)(Bt + (wc * 64 + ni * 16 + l16) * 32 + quad * 8);
#pragma unroll
    for (int mi = 0; mi < 4; ++mi)
#pragma unroll
      for (int ni = 0; ni < 4; ++ni)
        acc[mi][ni] = __builtin_amdgcn_mfma_f32_16x16x32_bf16(aF[mi], bF[ni], acc[mi][ni], 0, 0, 0);
    __syncthreads();
  }
  // epilogue: C/D layout col=lane&15, row=quad*4+reg
#pragma unroll
  for (int mi = 0; mi < 4; ++mi) {
#pragma unroll
    for (int ni = 0; ni < 4; ++ni) {
      const int col = bn * 128 + wc * 64 + ni * 16 + l16;
#pragma unroll
      for (int r = 0; r < 4; ++r) {
        const int row = bm * 64 + mi * 16 + quad * 4 + r;
        float v = acc[mi][ni][r];
        if (EPI == 1) {
          v += bias[(size_t)(row >> 11) * 1024 + col];
          v = v / (1.f + __expf(-v));
          ((unsigned short*)out)[(size_t)row * 1024 + col] = f2bf(v);
        } else {
          v += bias[col];
          ((float*)out)[(size_t)row * 1024 + col] = v;
        }
      }
    }
  }
}

// ---------- final LN over Y rows ----------
__global__ __launch_bounds__(256) void final_ln(
    const float* __restrict__ Y, const float* __restrict__ g,
    const float* __restrict__ be, float* __restrict__ out) {
  __shared__ float red[4];
  const int row = blockIdx.x;
  const int j = threadIdx.x * 4;
  float4 yv4 = *(const float4*)(Y + (size_t)row * 1024 + j);
  float yv[4] = { yv4.x, yv4.y, yv4.z, yv4.w };
  float s = yv[0] + yv[1] + yv[2] + yv[3];
  float ss = yv[0]*yv[0] + yv[1]*yv[1] + yv[2]*yv[2] + yv[3]*yv[3];
  s = block_sum256(s, red);
  ss = block_sum256(ss, red);
  const float mu = s * (1.f / 1024.f);
  const float rstd = rsqrtf(ss * (1.f / 1024.f) - mu * mu + EPS_LN);
  float4 g4 = *(const float4*)(g + j);
  float4 b4 = *(const float4*)(be + j);
  float4 o;
  o.x = (yv[0] - mu) * rstd * g4.x + b4.x;
  o.y = (yv[1] - mu) * rstd * g4.y + b4.y;
  o.z = (yv[2] - mu) * rstd * g4.z + b4.z;
  o.w = (yv[3] - mu) * rstd * g4.w + b4.w;
  *(float4*)(out + (size_t)row * 1024 + j) = o;
}

extern "C" void kernel_launch(void* const* d_in, const int* in_sizes, int n_in,
                              void* d_out, int out_size, void* d_ws, size_t ws_size,
                              hipStream_t stream) {
  const float* x   = (const float*)d_in[0];
  const int*   pid = (const int*)d_in[1];
  const int*   cid = (const int*)d_in[2];
  const int*   tms = (const int*)d_in[3];
  const int*   sct = (const int*)d_in[4];
  const float* mem = (const float*)d_in[5];
  const float* noi = (const float*)d_in[6];
  const float* res = (const float*)d_in[7];
  const float* pwg = (const float*)d_in[8];
  const float* pwb = (const float*)d_in[9];
  const float* cpg = (const float*)d_in[10];
  const float* cpb = (const float*)d_in[11];
  const float* tmg = (const float*)d_in[12];
  const float* tmb = (const float*)d_in[13];
  const float* msg = (const float*)d_in[14];
  const float* msb = (const float*)d_in[15];
  const float* mW1 = (const float*)d_in[16]; const float* mb1 = (const float*)d_in[17];
  const float* mW2 = (const float*)d_in[18]; const float* mb2 = (const float*)d_in[19];
  const float* mg  = (const float*)d_in[20]; const float* mbe = (const float*)d_in[21];
  const float* nW1 = (const float*)d_in[22]; const float* nb1 = (const float*)d_in[23];
  const float* nW2 = (const float*)d_in[24]; const float* nb2 = (const float*)d_in[25];
  const float* ng  = (const float*)d_in[26]; const float* nbe = (const float*)d_in[27];
  const float* rW1 = (const float*)d_in[28]; const float* rb1 = (const float*)d_in[29];
  const float* rW2 = (const float*)d_in[30]; const float* rb2 = (const float*)d_in[31];
  const float* rg  = (const float*)d_in[32]; const float* rbe = (const float*)d_in[33];
  const float* iW1 = (const float*)d_in[34]; const float* ib1 = (const float*)d_in[35];
  const float* iW2 = (const float*)d_in[36]; const float* ib2 = (const float*)d_in[37];
  const float* ig  = (const float*)d_in[38]; const float* ibe = (const float*)d_in[39];
  const float* aw  = (const float*)d_in[40];

  char* ws = (char*)d_ws;
  float* w6    = (float*)ws;          // 16 floats
  float* H1pre = w6 + 16;             // 12 x 1024
  float* Ys    = H1pre + 12288;       // 12 x 1024
  float* mnrv  = Ys + 12288;          // 4 x 3072 (batch-major, scaled LN outputs)
  float* bias1 = mnrv + 12288;        // 4 x 1024
  unsigned short* W1T  = (unsigned short*)(ws + (1ull << 20));          // 1024x4096 bf16 (8 MiB)
  unsigned short* W2T  = (unsigned short*)(ws + (9ull << 20));          // 1024x1024 bf16 (2 MiB)
  unsigned short* cat4 = (unsigned short*)(ws + (11ull << 20));         // 8192x4096 bf16 (64 MiB)
  unsigned short* Hb   = (unsigned short*)(ws + (75ull << 20));         // 8192x1024 bf16 (16 MiB)
  float* Ybuf          = (float*)cat4;  // reuse cat4 region (dead after GEMM1)

  setup_small<<<113, 256, 0, stream>>>(aw, mb1, nb1, rb1, mb2, nb2, rb2, ib1,
                                       w6, H1pre, Ys, bias1);
  state_h1_acc<<<dim3(8, 10), 256, 0, stream>>>(mem, noi, res, mW1, nW1, rW1, H1pre);
  state_y_acc<<<dim3(8, 16, 3), 256, 0, stream>>>(H1pre, mW2, nW2, rW2, Ys);
  state_ln<<<12, 256, 0, stream>>>(Ys, mg, mbe, ng, nbe, rg, rbe, w6, mnrv);
  bias1_kernel<<<dim3(8, 48), 256, 0, stream>>>(mnrv, iW1, bias1);
  build_w1t<<<dim3(128, 32), 256, 0, stream>>>(iW1, w6, W1T);
  build_w2t<<<dim3(32, 32), 256, 0, stream>>>(iW2, W2T);
  build_cat<<<8192, 256, 0, stream>>>(x, pid, cid, tms, sct,
                                      pwg, pwb, cpg, cpb, tmg, tmb, msg, msb, cat4);
  gemm_bt<1><<<dim3(128, 8), 128, 0, stream>>>(cat4, W1T, bias1, (void*)Hb, 4096);
  gemm_bt<2><<<dim3(128, 8), 128, 0, stream>>>(Hb, W2T, ib2, (void*)Ybuf, 1024);
  final_ln<<<8192, 256, 0, stream>>>(Ybuf, ig, ibe, (float*)d_out);
}

// Round 5
// 371.537 us; speedup vs baseline: 1.0916x; 1.0916x over previous
//
#include <hip/hip_runtime.h>
#include <cstdint>
#include <cstddef>

#define EPS_LN 1e-5f

typedef short bf16x8 __attribute__((ext_vector_type(8)));
typedef float f32x4 __attribute__((ext_vector_type(4)));
typedef unsigned int u32_gl __attribute__((address_space(1)));
typedef unsigned int u32_ld __attribute__((address_space(3)));

__device__ __forceinline__ unsigned short f2bf(float f) {
  union { float f; unsigned u; } v; v.f = f;
  unsigned r = v.u + 0x7fffu + ((v.u >> 16) & 1u);
  return (unsigned short)(r >> 16);
}

__device__ __forceinline__ void softmax6(const float* __restrict__ aw, float* w) {
  float m = aw[0];
  for (int i = 1; i < 6; ++i) m = fmaxf(m, aw[i]);
  float s = 0.f;
  for (int i = 0; i < 6; ++i) { w[i] = __expf(aw[i] - m); s += w[i]; }
  const float inv = 1.f / s;
  for (int i = 0; i < 6; ++i) w[i] *= inv;
}

// 256-thread block sum (4 waves of 64)
__device__ __forceinline__ float block_sum256(float v, float* red) {
  for (int m = 32; m > 0; m >>= 1) v += __shfl_xor(v, m, 64);
  const int lane = threadIdx.x & 63, w = threadIdx.x >> 6;
  if (lane == 0) red[w] = v;
  __syncthreads();
  float r = red[0] + red[1] + red[2] + red[3];
  __syncthreads();
  return r;
}

// ---------- split-K accumulate: H1pre[st*4+b][j] += sum_k state[b][k]*W1[k][j] (+b1 on first slice) ----------
__global__ __launch_bounds__(256) void state_h1_acc(
    const float* __restrict__ mem, const float* __restrict__ noi, const float* __restrict__ res,
    const float* __restrict__ mW1, const float* __restrict__ nW1, const float* __restrict__ rW1,
    const float* __restrict__ mb1, const float* __restrict__ nb1, const float* __restrict__ rb1,
    float* __restrict__ H1pre) {
  // grid dim3(8, 10): y 0..7 = mem K-slices of 64; y=8 noi (K=64); y=9 res (K=32)
  const int chunk = blockIdx.x, ks = blockIdx.y;
  const int j = chunk * 128 + (threadIdx.x & 127);
  const int half = threadIdx.x >> 7;
  int st, k0, klen, sstride;
  const float* W1; const float* sp; const float* b1;
  if (ks < 8)       { st = 0; W1 = mW1; sp = mem; b1 = mb1; sstride = 512; k0 = ks * 64 + half * 32; klen = 32; }
  else if (ks == 8) { st = 1; W1 = nW1; sp = noi; b1 = nb1; sstride = 64;  k0 = half * 32;           klen = 32; }
  else              { st = 2; W1 = rW1; sp = res; b1 = rb1; sstride = 32;  k0 = half * 16;           klen = 16; }
  float a0 = 0.f, a1 = 0.f, a2 = 0.f, a3 = 0.f;
  const float* wp = W1 + (size_t)k0 * 1024 + j;
  for (int it = 0; it < klen; ++it) {
    const float wv = wp[(size_t)it * 1024];
    const int k = k0 + it;
    a0 += sp[k] * wv;
    a1 += sp[sstride + k] * wv;
    a2 += sp[2 * sstride + k] * wv;
    a3 += sp[3 * sstride + k] * wv;
  }
  __shared__ float part[4][128];
  const int jl = threadIdx.x & 127;
  if (half) { part[0][jl] = a0; part[1][jl] = a1; part[2][jl] = a2; part[3][jl] = a3; }
  __syncthreads();
  if (!half) {
    const float bv = (ks == 0 || ks >= 8) ? b1[j] : 0.f;  // once per stack
    atomicAdd(&H1pre[(size_t)(st * 4 + 0) * 1024 + j], a0 + part[0][jl] + bv);
    atomicAdd(&H1pre[(size_t)(st * 4 + 1) * 1024 + j], a1 + part[1][jl] + bv);
    atomicAdd(&H1pre[(size_t)(st * 4 + 2) * 1024 + j], a2 + part[2][jl] + bv);
    atomicAdd(&H1pre[(size_t)(st * 4 + 3) * 1024 + j], a3 + part[3][jl] + bv);
  }
}

// ---------- split-K accumulate with inline silu on H1pre reads (+b2 on first slice) ----------
__global__ __launch_bounds__(256) void state_y_acc(
    const float* __restrict__ H1pre,
    const float* __restrict__ mW2, const float* __restrict__ nW2, const float* __restrict__ rW2,
    const float* __restrict__ mb2, const float* __restrict__ nb2, const float* __restrict__ rb2,
    float* __restrict__ Ys) {
  // grid dim3(8, 16, 3): col chunk, K-slice of 64, stack
  const int chunk = blockIdx.x, ks = blockIdx.y, st = blockIdx.z;
  const float* W2 = st == 0 ? mW2 : st == 1 ? nW2 : rW2;
  const float* b2 = st == 0 ? mb2 : st == 1 ? nb2 : rb2;
  const int j = chunk * 128 + (threadIdx.x & 127);
  const int half = threadIdx.x >> 7;
  const int k0 = ks * 64 + half * 32;
  const float* h1 = H1pre + (size_t)st * 4096;
  float a0 = 0.f, a1 = 0.f, a2 = 0.f, a3 = 0.f;
  const float* wp = W2 + (size_t)k0 * 1024 + j;
  for (int it = 0; it < 32; ++it) {
    const float wv = wp[(size_t)it * 1024];
    const int k = k0 + it;
    float h;
    h = h1[k];        a0 += (h / (1.f + __expf(-h))) * wv;
    h = h1[1024 + k]; a1 += (h / (1.f + __expf(-h))) * wv;
    h = h1[2048 + k]; a2 += (h / (1.f + __expf(-h))) * wv;
    h = h1[3072 + k]; a3 += (h / (1.f + __expf(-h))) * wv;
  }
  __shared__ float part[4][128];
  const int jl = threadIdx.x & 127;
  if (half) { part[0][jl] = a0; part[1][jl] = a1; part[2][jl] = a2; part[3][jl] = a3; }
  __syncthreads();
  if (!half) {
    const float bv = (ks == 0) ? b2[j] : 0.f;
    atomicAdd(&Ys[(size_t)(st * 4 + 0) * 1024 + j], a0 + part[0][jl] + bv);
    atomicAdd(&Ys[(size_t)(st * 4 + 1) * 1024 + j], a1 + part[1][jl] + bv);
    atomicAdd(&Ys[(size_t)(st * 4 + 2) * 1024 + j], a2 + part[2][jl] + bv);
    atomicAdd(&Ys[(size_t)(st * 4 + 3) * 1024 + j], a3 + part[3][jl] + bv);
  }
}

// ---------- state MLP stage 3: mnrv[b][st*1024+j] = w[2+st] * LN(Ys) ----------
__global__ __launch_bounds__(256) void state_ln(
    const float* __restrict__ Ys,
    const float* __restrict__ mg, const float* __restrict__ mbe,
    const float* __restrict__ ng, const float* __restrict__ nbe,
    const float* __restrict__ rg, const float* __restrict__ rbe,
    const float* __restrict__ aw, float* __restrict__ mnrv) {
  __shared__ float red[4];
  const int st = blockIdx.x >> 2, b = blockIdx.x & 3;
  const float* g  = st == 0 ? mg  : st == 1 ? ng  : rg;
  const float* be = st == 0 ? mbe : st == 1 ? nbe : rbe;
  const float* y = Ys + (size_t)blockIdx.x * 1024;
  const int j = threadIdx.x * 4;
  float4 yv4 = *(const float4*)(y + j);
  float yv[4] = { yv4.x, yv4.y, yv4.z, yv4.w };
  float s = yv[0] + yv[1] + yv[2] + yv[3];
  float ss = yv[0]*yv[0] + yv[1]*yv[1] + yv[2]*yv[2] + yv[3]*yv[3];
  s = block_sum256(s, red);
  ss = block_sum256(ss, red);
  const float mu = s * (1.f / 1024.f);
  const float rstd = rsqrtf(ss * (1.f / 1024.f) - mu * mu + EPS_LN);
  float4 g4 = *(const float4*)(g + j);
  float4 b4 = *(const float4*)(be + j);
  float w[6];
  softmax6(aw, w);
  const float sc = w[2 + st];
  float* out = mnrv + (size_t)b * 3072 + st * 1024;
  out[j]     = ((yv[0] - mu) * rstd * g4.x + b4.x) * sc;
  out[j + 1] = ((yv[1] - mu) * rstd * g4.y + b4.y) * sc;
  out[j + 2] = ((yv[2] - mu) * rstd * g4.z + b4.z) * sc;
  out[j + 3] = ((yv[3] - mu) * rstd * g4.w + b4.w) * sc;
}

// ---------- per-batch GEMM-1 bias, split-K parallel + atomicAdd (+ib1 on first slice) ----------
// bias1[b][j] += sum_g mnrv[b][g] * iW1[2048+g][j],  g in [0,3072)
__global__ __launch_bounds__(256) void bias1_kernel(
    const float* __restrict__ mnrv, const float* __restrict__ iW1,
    const float* __restrict__ ib1, float* __restrict__ bias1) {
  // grid: dim3(8, 48) = (col chunk of 128, K-slice of 64)
  const int chunk = blockIdx.x, ks = blockIdx.y;
  const int j = chunk * 128 + (threadIdx.x & 127);
  const int half = threadIdx.x >> 7;
  const int g0 = ks * 64 + half * 32;
  float acc0 = 0.f, acc1 = 0.f, acc2 = 0.f, acc3 = 0.f;
  const float* wp = iW1 + (size_t)(2048 + g0) * 1024 + j;
  for (int it = 0; it < 32; ++it) {
    const int g = g0 + it;
    const float wv = wp[(size_t)it * 1024];
    acc0 += mnrv[g] * wv;
    acc1 += mnrv[3072 + g] * wv;
    acc2 += mnrv[6144 + g] * wv;
    acc3 += mnrv[9216 + g] * wv;
  }
  __shared__ float part[4][128];
  const int jl = threadIdx.x & 127;
  if (half) { part[0][jl] = acc0; part[1][jl] = acc1; part[2][jl] = acc2; part[3][jl] = acc3; }
  __syncthreads();
  if (!half) {
    const float bv = (ks == 0) ? ib1[j] : 0.f;
    atomicAdd(&bias1[j],        acc0 + part[0][jl] + bv);
    atomicAdd(&bias1[1024 + j], acc1 + part[1][jl] + bv);
    atomicAdd(&bias1[2048 + j], acc2 + part[2][jl] + bv);
    atomicAdd(&bias1[3072 + j], acc3 + part[3][jl] + bv);
  }
}

// ---------- fused prep: build_cat (8192 blocks) + W1T (4096) + W2T (1024) ----------
__global__ __launch_bounds__(256) void prep_all(
    const float* __restrict__ x,
    const int* __restrict__ pid_, const int* __restrict__ cid_,
    const int* __restrict__ tid_, const int* __restrict__ sid_,
    const float* __restrict__ pwg, const float* __restrict__ pwb,
    const float* __restrict__ cpg, const float* __restrict__ cpb,
    const float* __restrict__ tmg, const float* __restrict__ tmb,
    const float* __restrict__ msg, const float* __restrict__ msb,
    const float* __restrict__ iW1, const float* __restrict__ iW2,
    const float* __restrict__ aw,
    unsigned short* __restrict__ cat4,
    unsigned short* __restrict__ W1T, unsigned short* __restrict__ W2T) {
  __shared__ float red[4];
  __shared__ float tile[32][33];
  int bi = blockIdx.x;
  if (bi < 8192) {
    // ---- build_cat row ----
    const int row = bi;
    const int j = threadIdx.x * 4;
    float4 xv4 = *(const float4*)(x + (size_t)row * 1024 + j);
    float xv[4] = { xv4.x, xv4.y, xv4.z, xv4.w };
    float s = xv[0] + xv[1] + xv[2] + xv[3];
    float ss = xv[0]*xv[0] + xv[1]*xv[1] + xv[2]*xv[2] + xv[3]*xv[3];
    s = block_sum256(s, red);
    ss = block_sum256(ss, red);
    const float mu = s * (1.f / 1024.f);
    const float rstd = rsqrtf(ss * (1.f / 1024.f) - mu * mu + EPS_LN);
    float xh[4];
    for (int q = 0; q < 4; ++q) xh[q] = (xv[q] - mu) * rstd;
    const int pid = pid_[row], cid = cid_[row], tmi = tid_[row], msi = sid_[row];
    unsigned short* crow = cat4 + (size_t)row * 4096;

    float4 g4 = *(const float4*)(pwg + (size_t)pid * 1024 + j);
    float4 b4 = *(const float4*)(pwb + (size_t)pid * 1024 + j);
    float h1[4];
    h1[0] = xh[0] * g4.x + b4.x; h1[1] = xh[1] * g4.y + b4.y;
    h1[2] = xh[2] * g4.z + b4.z; h1[3] = xh[3] * g4.w + b4.w;
    float s1 = h1[0] + h1[1] + h1[2] + h1[3];
    float ss1 = h1[0]*h1[0] + h1[1]*h1[1] + h1[2]*h1[2] + h1[3]*h1[3];
    s1 = block_sum256(s1, red);
    ss1 = block_sum256(ss1, red);
    const float mu1 = s1 * (1.f / 1024.f);
    const float rstd1 = rsqrtf(ss1 * (1.f / 1024.f) - mu1 * mu1 + EPS_LN);
    g4 = *(const float4*)(cpg + (size_t)cid * 1024 + j);
    b4 = *(const float4*)(cpb + (size_t)cid * 1024 + j);
    ushort4 o;
    o.x = f2bf((h1[0] - mu1) * rstd1 * g4.x + b4.x);
    o.y = f2bf((h1[1] - mu1) * rstd1 * g4.y + b4.y);
    o.z = f2bf((h1[2] - mu1) * rstd1 * g4.z + b4.z);
    o.w = f2bf((h1[3] - mu1) * rstd1 * g4.w + b4.w);
    *(ushort4*)(crow + j) = o;

    g4 = *(const float4*)(tmg + (size_t)tmi * 1024 + j);
    b4 = *(const float4*)(tmb + (size_t)tmi * 1024 + j);
    o.x = f2bf(xh[0] * g4.x + b4.x); o.y = f2bf(xh[1] * g4.y + b4.y);
    o.z = f2bf(xh[2] * g4.z + b4.z); o.w = f2bf(xh[3] * g4.w + b4.w);
    *(ushort4*)(crow + 1024 + j) = o;

    o.x = f2bf(xv[0]); o.y = f2bf(xv[1]); o.z = f2bf(xv[2]); o.w = f2bf(xv[3]);
    *(ushort4*)(crow + 2048 + j) = o;

    g4 = *(const float4*)(msg + (size_t)msi * 1024 + j);
    b4 = *(const float4*)(msb + (size_t)msi * 1024 + j);
    o.x = f2bf(xh[0] * g4.x + b4.x); o.y = f2bf(xh[1] * g4.y + b4.y);
    o.z = f2bf(xh[2] * g4.z + b4.z); o.w = f2bf(xh[3] * g4.w + b4.w);
    *(ushort4*)(crow + 3072 + j) = o;
    return;
  }
  bi -= 8192;
  float w[6];
  softmax6(aw, w);
  const int r = threadIdx.x >> 3;
  const int c = (threadIdx.x & 7) * 4;
  if (bi < 4096) {
    // ---- W1T tile: k0 = (bi&127)*32, n0 = (bi>>7)*32 ----
    const int k0 = (bi & 127) * 32, n0 = (bi >> 7) * 32;
    const int kk = k0 + r;
    float v[4];
    if (kk < 2048) {
      const float s = (kk < 1024) ? w[0] : w[1];
      float4 a = *(const float4*)(iW1 + (size_t)kk * 1024 + n0 + c);
      v[0] = s * a.x; v[1] = s * a.y; v[2] = s * a.z; v[3] = s * a.w;
    } else if (kk < 3072) {
      const float s2 = w[2], s3 = w[3], s4 = w[4];
      float4 a = *(const float4*)(iW1 + (size_t)kk * 1024 + n0 + c);
      float4 bq = *(const float4*)(iW1 + (size_t)(kk + 1024) * 1024 + n0 + c);
      float4 cq = *(const float4*)(iW1 + (size_t)(kk + 2048) * 1024 + n0 + c);
      v[0] = s2 * a.x + s3 * bq.x + s4 * cq.x;
      v[1] = s2 * a.y + s3 * bq.y + s4 * cq.y;
      v[2] = s2 * a.z + s3 * bq.z + s4 * cq.z;
      v[3] = s2 * a.w + s3 * bq.w + s4 * cq.w;
    } else {
      const float s = w[5];
      float4 a = *(const float4*)(iW1 + (size_t)(kk + 2048) * 1024 + n0 + c);
      v[0] = s * a.x; v[1] = s * a.y; v[2] = s * a.z; v[3] = s * a.w;
    }
    tile[r][c] = v[0]; tile[r][c + 1] = v[1]; tile[r][c + 2] = v[2]; tile[r][c + 3] = v[3];
    __syncthreads();
    const int nl = threadIdx.x >> 3;
    const int k4 = (threadIdx.x & 7) * 4;
    ushort4 o;
    o.x = f2bf(tile[k4][nl]);     o.y = f2bf(tile[k4 + 1][nl]);
    o.z = f2bf(tile[k4 + 2][nl]); o.w = f2bf(tile[k4 + 3][nl]);
    *(ushort4*)(W1T + (size_t)(n0 + nl) * 4096 + k0 + k4) = o;
    return;
  }
  bi -= 4096;
  {
    // ---- W2T tile: k0 = (bi&31)*32, n0 = (bi>>5)*32 ----
    const int k0 = (bi & 31) * 32, n0 = (bi >> 5) * 32;
    float4 a = *(const float4*)(iW2 + (size_t)(k0 + r) * 1024 + n0 + c);
    tile[r][c] = a.x; tile[r][c + 1] = a.y; tile[r][c + 2] = a.z; tile[r][c + 3] = a.w;
    __syncthreads();
    const int nl = threadIdx.x >> 3, k4 = (threadIdx.x & 7) * 4;
    ushort4 o;
    o.x = f2bf(tile[k4][nl]);     o.y = f2bf(tile[k4 + 1][nl]);
    o.z = f2bf(tile[k4 + 2][nl]); o.w = f2bf(tile[k4 + 3][nl]);
    *(ushort4*)(W2T + (size_t)(n0 + nl) * 1024 + k0 + k4) = o;
  }
}

// ---------- bf16 MFMA GEMM: C(M x 1024) = A(M x K) * BT(1024 x K)^T ----------
// 128x128 tile, 256 threads, TWO 32-wide K-subtiles per barrier pair (32 MFMA/barrier).
// EPI 1: + bias1[row>>11][col], silu, store bf16.  EPI 2: + bias[col], store fp32.
template <int EPI>
__global__ __launch_bounds__(256, 2) void gemm_bt(
    const unsigned short* __restrict__ A, const unsigned short* __restrict__ BT,
    const float* __restrict__ bias, void* __restrict__ out, int K) {
  __shared__ unsigned short At[2][128 * 32];
  __shared__ unsigned short Bt[2][128 * 32];
  const int t = threadIdx.x;
  const int lane = t & 63;
  const int wave = t >> 6;
  const int wr = wave >> 1, wc = wave & 1;
  const int quad = lane >> 4, l16 = lane & 15;
  const int bm = blockIdx.x, bn = blockIdx.y;
  const unsigned short* Ab = A + (size_t)bm * 128 * K;
  const unsigned short* Bb = BT + (size_t)bn * 128 * K;
  const int r0 = t >> 2, c0 = (t & 3) * 8;
  f32x4 acc[4][4];
#pragma unroll
  for (int i = 0; i < 4; ++i)
#pragma unroll
    for (int jj = 0; jj < 4; ++jj) { f32x4 z = {0.f, 0.f, 0.f, 0.f}; acc[i][jj] = z; }

  for (int kt = 0; kt < K; kt += 64) {
#pragma unroll
    for (int h = 0; h < 2; ++h) {
      const int ko = kt + h * 32;
      __builtin_amdgcn_global_load_lds(
          (const u32_gl*)(Ab + (size_t)r0 * K + ko + c0),
          (u32_ld*)(At[h] + t * 8), 16, 0, 0);
      __builtin_amdgcn_global_load_lds(
          (const u32_gl*)(Ab + (size_t)(r0 + 64) * K + ko + c0),
          (u32_ld*)(At[h] + (256 + t) * 8), 16, 0, 0);
      __builtin_amdgcn_global_load_lds(
          (const u32_gl*)(Bb + (size_t)r0 * K + ko + c0),
          (u32_ld*)(Bt[h] + t * 8), 16, 0, 0);
      __builtin_amdgcn_global_load_lds(
          (const u32_gl*)(Bb + (size_t)(r0 + 64) * K + ko + c0),
          (u32_ld*)(Bt[h] + (256 + t) * 8), 16, 0, 0);
    }
    __syncthreads();
#pragma unroll
    for (int h = 0; h < 2; ++h) {
      bf16x8 aF[4], bF[4];
#pragma unroll
      for (int mi = 0; mi < 4; ++mi)
        aF[mi] = *(const bf16x8*)(At[h] + (wr * 64 + mi * 16 + l16) * 32 + quad * 8);
#pragma unroll
      for (int ni = 0; ni < 4; ++ni)
        bF[ni] = *(const bf16x8*)(Bt[h] + (wc * 64 + ni * 16 + l16) * 32 + quad * 8);
#pragma unroll
      for (int mi = 0; mi < 4; ++mi)
#pragma unroll
        for (int ni = 0; ni < 4; ++ni)
          acc[mi][ni] = __builtin_amdgcn_mfma_f32_16x16x32_bf16(aF[mi], bF[ni], acc[mi][ni], 0, 0, 0);
    }
    __syncthreads();
  }
  // epilogue: C/D layout col=lane&15, row=quad*4+reg
#pragma unroll
  for (int mi = 0; mi < 4; ++mi) {
#pragma unroll
    for (int ni = 0; ni < 4; ++ni) {
      const int col = bn * 128 + wc * 64 + ni * 16 + l16;
#pragma unroll
      for (int r = 0; r < 4; ++r) {
        const int row = bm * 128 + wr * 64 + mi * 16 + quad * 4 + r;
        float v = acc[mi][ni][r];
        if (EPI == 1) {
          v += bias[(size_t)(row >> 11) * 1024 + col];
          v = v / (1.f + __expf(-v));
          ((unsigned short*)out)[(size_t)row * 1024 + col] = f2bf(v);
        } else {
          v += bias[col];
          ((float*)out)[(size_t)row * 1024 + col] = v;
        }
      }
    }
  }
}

// ---------- final LN over Y rows ----------
__global__ __launch_bounds__(256) void final_ln(
    const float* __restrict__ Y, const float* __restrict__ g,
    const float* __restrict__ be, float* __restrict__ out) {
  __shared__ float red[4];
  const int row = blockIdx.x;
  const int j = threadIdx.x * 4;
  float4 yv4 = *(const float4*)(Y + (size_t)row * 1024 + j);
  float yv[4] = { yv4.x, yv4.y, yv4.z, yv4.w };
  float s = yv[0] + yv[1] + yv[2] + yv[3];
  float ss = yv[0]*yv[0] + yv[1]*yv[1] + yv[2]*yv[2] + yv[3]*yv[3];
  s = block_sum256(s, red);
  ss = block_sum256(ss, red);
  const float mu = s * (1.f / 1024.f);
  const float rstd = rsqrtf(ss * (1.f / 1024.f) - mu * mu + EPS_LN);
  float4 g4 = *(const float4*)(g + j);
  float4 b4 = *(const float4*)(be + j);
  float4 o;
  o.x = (yv[0] - mu) * rstd * g4.x + b4.x;
  o.y = (yv[1] - mu) * rstd * g4.y + b4.y;
  o.z = (yv[2] - mu) * rstd * g4.z + b4.z;
  o.w = (yv[3] - mu) * rstd * g4.w + b4.w;
  *(float4*)(out + (size_t)row * 1024 + j) = o;
}

extern "C" void kernel_launch(void* const* d_in, const int* in_sizes, int n_in,
                              void* d_out, int out_size, void* d_ws, size_t ws_size,
                              hipStream_t stream) {
  const float* x   = (const float*)d_in[0];
  const int*   pid = (const int*)d_in[1];
  const int*   cid = (const int*)d_in[2];
  const int*   tms = (const int*)d_in[3];
  const int*   sct = (const int*)d_in[4];
  const float* mem = (const float*)d_in[5];
  const float* noi = (const float*)d_in[6];
  const float* res = (const float*)d_in[7];
  const float* pwg = (const float*)d_in[8];
  const float* pwb = (const float*)d_in[9];
  const float* cpg = (const float*)d_in[10];
  const float* cpb = (const float*)d_in[11];
  const float* tmg = (const float*)d_in[12];
  const float* tmb = (const float*)d_in[13];
  const float* msg = (const float*)d_in[14];
  const float* msb = (const float*)d_in[15];
  const float* mW1 = (const float*)d_in[16]; const float* mb1 = (const float*)d_in[17];
  const float* mW2 = (const float*)d_in[18]; const float* mb2 = (const float*)d_in[19];
  const float* mg  = (const float*)d_in[20]; const float* mbe = (const float*)d_in[21];
  const float* nW1 = (const float*)d_in[22]; const float* nb1 = (const float*)d_in[23];
  const float* nW2 = (const float*)d_in[24]; const float* nb2 = (const float*)d_in[25];
  const float* ng  = (const float*)d_in[26]; const float* nbe = (const float*)d_in[27];
  const float* rW1 = (const float*)d_in[28]; const float* rb1 = (const float*)d_in[29];
  const float* rW2 = (const float*)d_in[30]; const float* rb2 = (const float*)d_in[31];
  const float* rg  = (const float*)d_in[32]; const float* rbe = (const float*)d_in[33];
  const float* iW1 = (const float*)d_in[34]; const float* ib1 = (const float*)d_in[35];
  const float* iW2 = (const float*)d_in[36]; const float* ib2 = (const float*)d_in[37];
  const float* ig  = (const float*)d_in[38]; const float* ibe = (const float*)d_in[39];
  const float* aw  = (const float*)d_in[40];

  char* ws = (char*)d_ws;
  float* H1pre = (float*)ws;          // 12 x 1024
  float* Ys    = H1pre + 12288;       // 12 x 1024
  float* bias1 = Ys + 12288;          // 4 x 1024
  float* mnrv  = bias1 + 4096;        // 4 x 3072 (batch-major, scaled LN outputs)
  unsigned short* W1T  = (unsigned short*)(ws + (1ull << 20));          // 1024x4096 bf16 (8 MiB)
  unsigned short* W2T  = (unsigned short*)(ws + (9ull << 20));          // 1024x1024 bf16 (2 MiB)
  unsigned short* cat4 = (unsigned short*)(ws + (11ull << 20));         // 8192x4096 bf16 (64 MiB)
  unsigned short* Hb   = (unsigned short*)(ws + (75ull << 20));         // 8192x1024 bf16 (16 MiB)
  float* Ybuf          = (float*)cat4;  // reuse cat4 region (dead after GEMM1)

  // zero H1pre + Ys + bias1 (bias folded into split-K kernels' first slice)
  hipMemsetAsync(ws, 0, (12288 + 12288 + 4096) * sizeof(float), stream);
  state_h1_acc<<<dim3(8, 10), 256, 0, stream>>>(mem, noi, res, mW1, nW1, rW1,
                                                mb1, nb1, rb1, H1pre);
  state_y_acc<<<dim3(8, 16, 3), 256, 0, stream>>>(H1pre, mW2, nW2, rW2,
                                                  mb2, nb2, rb2, Ys);
  state_ln<<<12, 256, 0, stream>>>(Ys, mg, mbe, ng, nbe, rg, rbe, aw, mnrv);
  bias1_kernel<<<dim3(8, 48), 256, 0, stream>>>(mnrv, iW1, ib1, bias1);
  prep_all<<<8192 + 4096 + 1024, 256, 0, stream>>>(
      x, pid, cid, tms, sct, pwg, pwb, cpg, cpb, tmg, tmb, msg, msb,
      iW1, iW2, aw, cat4, W1T, W2T);
  gemm_bt<1><<<dim3(64, 8), 256, 0, stream>>>(cat4, W1T, bias1, (void*)Hb, 4096);
  gemm_bt<2><<<dim3(64, 8), 256, 0, stream>>>(Hb, W2T, ib2, (void*)Ybuf, 1024);
  final_ln<<<8192, 256, 0, stream>>>(Ybuf, ig, ibe, (float*)d_out);
}

// Round 6
// 364.480 us; speedup vs baseline: 1.1127x; 1.0194x over previous
//
#include <hip/hip_runtime.h>
#include <cstdint>
#include <cstddef>

#define EPS_LN 1e-5f

typedef short bf16x8 __attribute__((ext_vector_type(8)));
typedef float f32x4 __attribute__((ext_vector_type(4)));
typedef unsigned int u32_gl __attribute__((address_space(1)));
typedef unsigned int u32_ld __attribute__((address_space(3)));

__device__ __forceinline__ unsigned short f2bf(float f) {
  union { float f; unsigned u; } v; v.f = f;
  unsigned r = v.u + 0x7fffu + ((v.u >> 16) & 1u);
  return (unsigned short)(r >> 16);
}

__device__ __forceinline__ float bf2f(unsigned short b) {
  union { unsigned u; float f; } v; v.u = ((unsigned)b) << 16;
  return v.f;
}

__device__ __forceinline__ void softmax6(const float* __restrict__ aw, float* w) {
  float m = aw[0];
  for (int i = 1; i < 6; ++i) m = fmaxf(m, aw[i]);
  float s = 0.f;
  for (int i = 0; i < 6; ++i) { w[i] = __expf(aw[i] - m); s += w[i]; }
  const float inv = 1.f / s;
  for (int i = 0; i < 6; ++i) w[i] *= inv;
}

// 256-thread block sum (4 waves of 64)
__device__ __forceinline__ float block_sum256(float v, float* red) {
  for (int m = 32; m > 0; m >>= 1) v += __shfl_xor(v, m, 64);
  const int lane = threadIdx.x & 63, w = threadIdx.x >> 6;
  if (lane == 0) red[w] = v;
  __syncthreads();
  float r = red[0] + red[1] + red[2] + red[3];
  __syncthreads();
  return r;
}

// ---------- split-K accumulate: H1pre[st*4+b][j] += sum_k state[b][k]*W1[k][j] (+b1 on first slice) ----------
__global__ __launch_bounds__(256) void state_h1_acc(
    const float* __restrict__ mem, const float* __restrict__ noi, const float* __restrict__ res,
    const float* __restrict__ mW1, const float* __restrict__ nW1, const float* __restrict__ rW1,
    const float* __restrict__ mb1, const float* __restrict__ nb1, const float* __restrict__ rb1,
    float* __restrict__ H1pre) {
  // grid dim3(8, 10): y 0..7 = mem K-slices of 64; y=8 noi (K=64); y=9 res (K=32)
  const int chunk = blockIdx.x, ks = blockIdx.y;
  const int j = chunk * 128 + (threadIdx.x & 127);
  const int half = threadIdx.x >> 7;
  int st, k0, klen, sstride;
  const float* W1; const float* sp; const float* b1;
  if (ks < 8)       { st = 0; W1 = mW1; sp = mem; b1 = mb1; sstride = 512; k0 = ks * 64 + half * 32; klen = 32; }
  else if (ks == 8) { st = 1; W1 = nW1; sp = noi; b1 = nb1; sstride = 64;  k0 = half * 32;           klen = 32; }
  else              { st = 2; W1 = rW1; sp = res; b1 = rb1; sstride = 32;  k0 = half * 16;           klen = 16; }
  float a0 = 0.f, a1 = 0.f, a2 = 0.f, a3 = 0.f;
  const float* wp = W1 + (size_t)k0 * 1024 + j;
  for (int it = 0; it < klen; ++it) {
    const float wv = wp[(size_t)it * 1024];
    const int k = k0 + it;
    a0 += sp[k] * wv;
    a1 += sp[sstride + k] * wv;
    a2 += sp[2 * sstride + k] * wv;
    a3 += sp[3 * sstride + k] * wv;
  }
  __shared__ float part[4][128];
  const int jl = threadIdx.x & 127;
  if (half) { part[0][jl] = a0; part[1][jl] = a1; part[2][jl] = a2; part[3][jl] = a3; }
  __syncthreads();
  if (!half) {
    const float bv = (ks == 0 || ks >= 8) ? b1[j] : 0.f;  // once per stack
    atomicAdd(&H1pre[(size_t)(st * 4 + 0) * 1024 + j], a0 + part[0][jl] + bv);
    atomicAdd(&H1pre[(size_t)(st * 4 + 1) * 1024 + j], a1 + part[1][jl] + bv);
    atomicAdd(&H1pre[(size_t)(st * 4 + 2) * 1024 + j], a2 + part[2][jl] + bv);
    atomicAdd(&H1pre[(size_t)(st * 4 + 3) * 1024 + j], a3 + part[3][jl] + bv);
  }
}

// ---------- split-K accumulate with inline silu on H1pre reads (+b2 on first slice) ----------
__global__ __launch_bounds__(256) void state_y_acc(
    const float* __restrict__ H1pre,
    const float* __restrict__ mW2, const float* __restrict__ nW2, const float* __restrict__ rW2,
    const float* __restrict__ mb2, const float* __restrict__ nb2, const float* __restrict__ rb2,
    float* __restrict__ Ys) {
  // grid dim3(8, 16, 3): col chunk, K-slice of 64, stack
  const int chunk = blockIdx.x, ks = blockIdx.y, st = blockIdx.z;
  const float* W2 = st == 0 ? mW2 : st == 1 ? nW2 : rW2;
  const float* b2 = st == 0 ? mb2 : st == 1 ? nb2 : rb2;
  const int j = chunk * 128 + (threadIdx.x & 127);
  const int half = threadIdx.x >> 7;
  const int k0 = ks * 64 + half * 32;
  const float* h1 = H1pre + (size_t)st * 4096;
  float a0 = 0.f, a1 = 0.f, a2 = 0.f, a3 = 0.f;
  const float* wp = W2 + (size_t)k0 * 1024 + j;
  for (int it = 0; it < 32; ++it) {
    const float wv = wp[(size_t)it * 1024];
    const int k = k0 + it;
    float h;
    h = h1[k];        a0 += (h / (1.f + __expf(-h))) * wv;
    h = h1[1024 + k]; a1 += (h / (1.f + __expf(-h))) * wv;
    h = h1[2048 + k]; a2 += (h / (1.f + __expf(-h))) * wv;
    h = h1[3072 + k]; a3 += (h / (1.f + __expf(-h))) * wv;
  }
  __shared__ float part[4][128];
  const int jl = threadIdx.x & 127;
  if (half) { part[0][jl] = a0; part[1][jl] = a1; part[2][jl] = a2; part[3][jl] = a3; }
  __syncthreads();
  if (!half) {
    const float bv = (ks == 0) ? b2[j] : 0.f;
    atomicAdd(&Ys[(size_t)(st * 4 + 0) * 1024 + j], a0 + part[0][jl] + bv);
    atomicAdd(&Ys[(size_t)(st * 4 + 1) * 1024 + j], a1 + part[1][jl] + bv);
    atomicAdd(&Ys[(size_t)(st * 4 + 2) * 1024 + j], a2 + part[2][jl] + bv);
    atomicAdd(&Ys[(size_t)(st * 4 + 3) * 1024 + j], a3 + part[3][jl] + bv);
  }
}

// ---------- state MLP stage 3: mnrv[b][st*1024+j] = w[2+st] * LN(Ys) ----------
__global__ __launch_bounds__(256) void state_ln(
    const float* __restrict__ Ys,
    const float* __restrict__ mg, const float* __restrict__ mbe,
    const float* __restrict__ ng, const float* __restrict__ nbe,
    const float* __restrict__ rg, const float* __restrict__ rbe,
    const float* __restrict__ aw, float* __restrict__ mnrv) {
  __shared__ float red[4];
  const int st = blockIdx.x >> 2, b = blockIdx.x & 3;
  const float* g  = st == 0 ? mg  : st == 1 ? ng  : rg;
  const float* be = st == 0 ? mbe : st == 1 ? nbe : rbe;
  const float* y = Ys + (size_t)blockIdx.x * 1024;
  const int j = threadIdx.x * 4;
  float4 yv4 = *(const float4*)(y + j);
  float yv[4] = { yv4.x, yv4.y, yv4.z, yv4.w };
  float s = yv[0] + yv[1] + yv[2] + yv[3];
  float ss = yv[0]*yv[0] + yv[1]*yv[1] + yv[2]*yv[2] + yv[3]*yv[3];
  s = block_sum256(s, red);
  ss = block_sum256(ss, red);
  const float mu = s * (1.f / 1024.f);
  const float rstd = rsqrtf(ss * (1.f / 1024.f) - mu * mu + EPS_LN);
  float4 g4 = *(const float4*)(g + j);
  float4 b4 = *(const float4*)(be + j);
  float w[6];
  softmax6(aw, w);
  const float sc = w[2 + st];
  float* out = mnrv + (size_t)b * 3072 + st * 1024;
  out[j]     = ((yv[0] - mu) * rstd * g4.x + b4.x) * sc;
  out[j + 1] = ((yv[1] - mu) * rstd * g4.y + b4.y) * sc;
  out[j + 2] = ((yv[2] - mu) * rstd * g4.z + b4.z) * sc;
  out[j + 3] = ((yv[3] - mu) * rstd * g4.w + b4.w) * sc;
}

// ---------- fused prep: build_cat (8192) + W1T (4096) + W2T (1024) + bias1 (384) ----------
__global__ __launch_bounds__(256) void prep_all(
    const float* __restrict__ x,
    const int* __restrict__ pid_, const int* __restrict__ cid_,
    const int* __restrict__ tid_, const int* __restrict__ sid_,
    const float* __restrict__ pwg, const float* __restrict__ pwb,
    const float* __restrict__ cpg, const float* __restrict__ cpb,
    const float* __restrict__ tmg, const float* __restrict__ tmb,
    const float* __restrict__ msg, const float* __restrict__ msb,
    const float* __restrict__ iW1, const float* __restrict__ iW2,
    const float* __restrict__ aw, const float* __restrict__ mnrv,
    const float* __restrict__ ib1,
    unsigned short* __restrict__ cat4,
    unsigned short* __restrict__ W1T, unsigned short* __restrict__ W2T,
    float* __restrict__ bias1) {
  __shared__ float red[4];
  __shared__ float tile[32][33];
  __shared__ float part[4][128];
  int bi = blockIdx.x;
  if (bi < 8192) {
    // ---- build_cat row ----
    const int row = bi;
    const int j = threadIdx.x * 4;
    float4 xv4 = *(const float4*)(x + (size_t)row * 1024 + j);
    float xv[4] = { xv4.x, xv4.y, xv4.z, xv4.w };
    float s = xv[0] + xv[1] + xv[2] + xv[3];
    float ss = xv[0]*xv[0] + xv[1]*xv[1] + xv[2]*xv[2] + xv[3]*xv[3];
    s = block_sum256(s, red);
    ss = block_sum256(ss, red);
    const float mu = s * (1.f / 1024.f);
    const float rstd = rsqrtf(ss * (1.f / 1024.f) - mu * mu + EPS_LN);
    float xh[4];
    for (int q = 0; q < 4; ++q) xh[q] = (xv[q] - mu) * rstd;
    const int pid = pid_[row], cid = cid_[row], tmi = tid_[row], msi = sid_[row];
    unsigned short* crow = cat4 + (size_t)row * 4096;

    float4 g4 = *(const float4*)(pwg + (size_t)pid * 1024 + j);
    float4 b4 = *(const float4*)(pwb + (size_t)pid * 1024 + j);
    float h1[4];
    h1[0] = xh[0] * g4.x + b4.x; h1[1] = xh[1] * g4.y + b4.y;
    h1[2] = xh[2] * g4.z + b4.z; h1[3] = xh[3] * g4.w + b4.w;
    float s1 = h1[0] + h1[1] + h1[2] + h1[3];
    float ss1 = h1[0]*h1[0] + h1[1]*h1[1] + h1[2]*h1[2] + h1[3]*h1[3];
    s1 = block_sum256(s1, red);
    ss1 = block_sum256(ss1, red);
    const float mu1 = s1 * (1.f / 1024.f);
    const float rstd1 = rsqrtf(ss1 * (1.f / 1024.f) - mu1 * mu1 + EPS_LN);
    g4 = *(const float4*)(cpg + (size_t)cid * 1024 + j);
    b4 = *(const float4*)(cpb + (size_t)cid * 1024 + j);
    ushort4 o;
    o.x = f2bf((h1[0] - mu1) * rstd1 * g4.x + b4.x);
    o.y = f2bf((h1[1] - mu1) * rstd1 * g4.y + b4.y);
    o.z = f2bf((h1[2] - mu1) * rstd1 * g4.z + b4.z);
    o.w = f2bf((h1[3] - mu1) * rstd1 * g4.w + b4.w);
    *(ushort4*)(crow + j) = o;

    g4 = *(const float4*)(tmg + (size_t)tmi * 1024 + j);
    b4 = *(const float4*)(tmb + (size_t)tmi * 1024 + j);
    o.x = f2bf(xh[0] * g4.x + b4.x); o.y = f2bf(xh[1] * g4.y + b4.y);
    o.z = f2bf(xh[2] * g4.z + b4.z); o.w = f2bf(xh[3] * g4.w + b4.w);
    *(ushort4*)(crow + 1024 + j) = o;

    o.x = f2bf(xv[0]); o.y = f2bf(xv[1]); o.z = f2bf(xv[2]); o.w = f2bf(xv[3]);
    *(ushort4*)(crow + 2048 + j) = o;

    g4 = *(const float4*)(msg + (size_t)msi * 1024 + j);
    b4 = *(const float4*)(msb + (size_t)msi * 1024 + j);
    o.x = f2bf(xh[0] * g4.x + b4.x); o.y = f2bf(xh[1] * g4.y + b4.y);
    o.z = f2bf(xh[2] * g4.z + b4.z); o.w = f2bf(xh[3] * g4.w + b4.w);
    *(ushort4*)(crow + 3072 + j) = o;
    return;
  }
  bi -= 8192;
  if (bi < 4096) {
    // ---- W1T tile: k0 = (bi&127)*32, n0 = (bi>>7)*32 ----
    float w[6];
    softmax6(aw, w);
    const int r = threadIdx.x >> 3;
    const int c = (threadIdx.x & 7) * 4;
    const int k0 = (bi & 127) * 32, n0 = (bi >> 7) * 32;
    const int kk = k0 + r;
    float v[4];
    if (kk < 2048) {
      const float s = (kk < 1024) ? w[0] : w[1];
      float4 a = *(const float4*)(iW1 + (size_t)kk * 1024 + n0 + c);
      v[0] = s * a.x; v[1] = s * a.y; v[2] = s * a.z; v[3] = s * a.w;
    } else if (kk < 3072) {
      const float s2 = w[2], s3 = w[3], s4 = w[4];
      float4 a = *(const float4*)(iW1 + (size_t)kk * 1024 + n0 + c);
      float4 bq = *(const float4*)(iW1 + (size_t)(kk + 1024) * 1024 + n0 + c);
      float4 cq = *(const float4*)(iW1 + (size_t)(kk + 2048) * 1024 + n0 + c);
      v[0] = s2 * a.x + s3 * bq.x + s4 * cq.x;
      v[1] = s2 * a.y + s3 * bq.y + s4 * cq.y;
      v[2] = s2 * a.z + s3 * bq.z + s4 * cq.z;
      v[3] = s2 * a.w + s3 * bq.w + s4 * cq.w;
    } else {
      const float s = w[5];
      float4 a = *(const float4*)(iW1 + (size_t)(kk + 2048) * 1024 + n0 + c);
      v[0] = s * a.x; v[1] = s * a.y; v[2] = s * a.z; v[3] = s * a.w;
    }
    tile[r][c] = v[0]; tile[r][c + 1] = v[1]; tile[r][c + 2] = v[2]; tile[r][c + 3] = v[3];
    __syncthreads();
    const int nl = threadIdx.x >> 3;
    const int k4 = (threadIdx.x & 7) * 4;
    ushort4 o;
    o.x = f2bf(tile[k4][nl]);     o.y = f2bf(tile[k4 + 1][nl]);
    o.z = f2bf(tile[k4 + 2][nl]); o.w = f2bf(tile[k4 + 3][nl]);
    *(ushort4*)(W1T + (size_t)(n0 + nl) * 4096 + k0 + k4) = o;
    return;
  }
  bi -= 4096;
  if (bi < 1024) {
    // ---- W2T tile: k0 = (bi&31)*32, n0 = (bi>>5)*32 ----
    const int r = threadIdx.x >> 3;
    const int c = (threadIdx.x & 7) * 4;
    const int k0 = (bi & 31) * 32, n0 = (bi >> 5) * 32;
    float4 a = *(const float4*)(iW2 + (size_t)(k0 + r) * 1024 + n0 + c);
    tile[r][c] = a.x; tile[r][c + 1] = a.y; tile[r][c + 2] = a.z; tile[r][c + 3] = a.w;
    __syncthreads();
    const int nl = threadIdx.x >> 3, k4 = (threadIdx.x & 7) * 4;
    ushort4 o;
    o.x = f2bf(tile[k4][nl]);     o.y = f2bf(tile[k4 + 1][nl]);
    o.z = f2bf(tile[k4 + 2][nl]); o.w = f2bf(tile[k4 + 3][nl]);
    *(ushort4*)(W2T + (size_t)(n0 + nl) * 1024 + k0 + k4) = o;
    return;
  }
  bi -= 1024;
  {
    // ---- bias1 split-K: 384 blocks: chunk = bi&7 (col*128), ks = bi>>3 (K-slice of 64) ----
    const int chunk = bi & 7, ks = bi >> 3;
    const int j = chunk * 128 + (threadIdx.x & 127);
    const int half = threadIdx.x >> 7;
    const int g0 = ks * 64 + half * 32;
    float acc0 = 0.f, acc1 = 0.f, acc2 = 0.f, acc3 = 0.f;
    const float* wp = iW1 + (size_t)(2048 + g0) * 1024 + j;
    for (int it = 0; it < 32; ++it) {
      const int g = g0 + it;
      const float wv = wp[(size_t)it * 1024];
      acc0 += mnrv[g] * wv;
      acc1 += mnrv[3072 + g] * wv;
      acc2 += mnrv[6144 + g] * wv;
      acc3 += mnrv[9216 + g] * wv;
    }
    const int jl = threadIdx.x & 127;
    if (half) { part[0][jl] = acc0; part[1][jl] = acc1; part[2][jl] = acc2; part[3][jl] = acc3; }
    __syncthreads();
    if (!half) {
      const float bv = (ks == 0) ? ib1[j] : 0.f;
      atomicAdd(&bias1[j],        acc0 + part[0][jl] + bv);
      atomicAdd(&bias1[1024 + j], acc1 + part[1][jl] + bv);
      atomicAdd(&bias1[2048 + j], acc2 + part[2][jl] + bv);
      atomicAdd(&bias1[3072 + j], acc3 + part[3][jl] + bv);
    }
  }
}

// ---------- bf16 MFMA GEMM: C(M x 1024) = A(M x K) * BT(1024 x K)^T ----------
// 128x128 tile, 256 threads, FOUR 32-wide K-subtiles per barrier pair (64 MFMA/barrier).
// LDS 64 KB/block; grid-limited 2 blocks/CU so no occupancy cost.
// EPI 1: + bias1[row>>11][col], silu, store bf16.  EPI 2: + bias[col], store bf16.
template <int EPI>
__global__ __launch_bounds__(256, 2) void gemm_bt(
    const unsigned short* __restrict__ A, const unsigned short* __restrict__ BT,
    const float* __restrict__ bias, void* __restrict__ out, int K) {
  __shared__ unsigned short At[4][128 * 32];
  __shared__ unsigned short Bt[4][128 * 32];
  const int t = threadIdx.x;
  const int lane = t & 63;
  const int wave = t >> 6;
  const int wr = wave >> 1, wc = wave & 1;
  const int quad = lane >> 4, l16 = lane & 15;
  const int bm = blockIdx.x, bn = blockIdx.y;
  const unsigned short* Ab = A + (size_t)bm * 128 * K;
  const unsigned short* Bb = BT + (size_t)bn * 128 * K;
  const int r0 = t >> 2, c0 = (t & 3) * 8;
  f32x4 acc[4][4];
#pragma unroll
  for (int i = 0; i < 4; ++i)
#pragma unroll
    for (int jj = 0; jj < 4; ++jj) { f32x4 z = {0.f, 0.f, 0.f, 0.f}; acc[i][jj] = z; }

  for (int kt = 0; kt < K; kt += 128) {
#pragma unroll
    for (int h = 0; h < 4; ++h) {
      const int ko = kt + h * 32;
      __builtin_amdgcn_global_load_lds(
          (const u32_gl*)(Ab + (size_t)r0 * K + ko + c0),
          (u32_ld*)(At[h] + t * 8), 16, 0, 0);
      __builtin_amdgcn_global_load_lds(
          (const u32_gl*)(Ab + (size_t)(r0 + 64) * K + ko + c0),
          (u32_ld*)(At[h] + (256 + t) * 8), 16, 0, 0);
      __builtin_amdgcn_global_load_lds(
          (const u32_gl*)(Bb + (size_t)r0 * K + ko + c0),
          (u32_ld*)(Bt[h] + t * 8), 16, 0, 0);
      __builtin_amdgcn_global_load_lds(
          (const u32_gl*)(Bb + (size_t)(r0 + 64) * K + ko + c0),
          (u32_ld*)(Bt[h] + (256 + t) * 8), 16, 0, 0);
    }
    __syncthreads();
#pragma unroll
    for (int h = 0; h < 4; ++h) {
      bf16x8 aF[4], bF[4];
#pragma unroll
      for (int mi = 0; mi < 4; ++mi)
        aF[mi] = *(const bf16x8*)(At[h] + (wr * 64 + mi * 16 + l16) * 32 + quad * 8);
#pragma unroll
      for (int ni = 0; ni < 4; ++ni)
        bF[ni] = *(const bf16x8*)(Bt[h] + (wc * 64 + ni * 16 + l16) * 32 + quad * 8);
#pragma unroll
      for (int mi = 0; mi < 4; ++mi)
#pragma unroll
        for (int ni = 0; ni < 4; ++ni)
          acc[mi][ni] = __builtin_amdgcn_mfma_f32_16x16x32_bf16(aF[mi], bF[ni], acc[mi][ni], 0, 0, 0);
    }
    __syncthreads();
  }
  // epilogue: C/D layout col=lane&15, row=quad*4+reg
#pragma unroll
  for (int mi = 0; mi < 4; ++mi) {
#pragma unroll
    for (int ni = 0; ni < 4; ++ni) {
      const int col = bn * 128 + wc * 64 + ni * 16 + l16;
#pragma unroll
      for (int r = 0; r < 4; ++r) {
        const int row = bm * 128 + wr * 64 + mi * 16 + quad * 4 + r;
        float v = acc[mi][ni][r];
        if (EPI == 1) {
          v += bias[(size_t)(row >> 11) * 1024 + col];
          v = v / (1.f + __expf(-v));
          ((unsigned short*)out)[(size_t)row * 1024 + col] = f2bf(v);
        } else {
          v += bias[col];
          ((unsigned short*)out)[(size_t)row * 1024 + col] = f2bf(v);
        }
      }
    }
  }
}

// ---------- final LN over bf16 Y rows, fp32 out ----------
__global__ __launch_bounds__(256) void final_ln(
    const unsigned short* __restrict__ Y, const float* __restrict__ g,
    const float* __restrict__ be, float* __restrict__ out) {
  __shared__ float red[4];
  const int row = blockIdx.x;
  const int j = threadIdx.x * 4;
  ushort4 u = *(const ushort4*)(Y + (size_t)row * 1024 + j);
  float yv[4] = { bf2f(u.x), bf2f(u.y), bf2f(u.z), bf2f(u.w) };
  float s = yv[0] + yv[1] + yv[2] + yv[3];
  float ss = yv[0]*yv[0] + yv[1]*yv[1] + yv[2]*yv[2] + yv[3]*yv[3];
  s = block_sum256(s, red);
  ss = block_sum256(ss, red);
  const float mu = s * (1.f / 1024.f);
  const float rstd = rsqrtf(ss * (1.f / 1024.f) - mu * mu + EPS_LN);
  float4 g4 = *(const float4*)(g + j);
  float4 b4 = *(const float4*)(be + j);
  float4 o;
  o.x = (yv[0] - mu) * rstd * g4.x + b4.x;
  o.y = (yv[1] - mu) * rstd * g4.y + b4.y;
  o.z = (yv[2] - mu) * rstd * g4.z + b4.z;
  o.w = (yv[3] - mu) * rstd * g4.w + b4.w;
  *(float4*)(out + (size_t)row * 1024 + j) = o;
}

extern "C" void kernel_launch(void* const* d_in, const int* in_sizes, int n_in,
                              void* d_out, int out_size, void* d_ws, size_t ws_size,
                              hipStream_t stream) {
  const float* x   = (const float*)d_in[0];
  const int*   pid = (const int*)d_in[1];
  const int*   cid = (const int*)d_in[2];
  const int*   tms = (const int*)d_in[3];
  const int*   sct = (const int*)d_in[4];
  const float* mem = (const float*)d_in[5];
  const float* noi = (const float*)d_in[6];
  const float* res = (const float*)d_in[7];
  const float* pwg = (const float*)d_in[8];
  const float* pwb = (const float*)d_in[9];
  const float* cpg = (const float*)d_in[10];
  const float* cpb = (const float*)d_in[11];
  const float* tmg = (const float*)d_in[12];
  const float* tmb = (const float*)d_in[13];
  const float* msg = (const float*)d_in[14];
  const float* msb = (const float*)d_in[15];
  const float* mW1 = (const float*)d_in[16]; const float* mb1 = (const float*)d_in[17];
  const float* mW2 = (const float*)d_in[18]; const float* mb2 = (const float*)d_in[19];
  const float* mg  = (const float*)d_in[20]; const float* mbe = (const float*)d_in[21];
  const float* nW1 = (const float*)d_in[22]; const float* nb1 = (const float*)d_in[23];
  const float* nW2 = (const float*)d_in[24]; const float* nb2 = (const float*)d_in[25];
  const float* ng  = (const float*)d_in[26]; const float* nbe = (const float*)d_in[27];
  const float* rW1 = (const float*)d_in[28]; const float* rb1 = (const float*)d_in[29];
  const float* rW2 = (const float*)d_in[30]; const float* rb2 = (const float*)d_in[31];
  const float* rg  = (const float*)d_in[32]; const float* rbe = (const float*)d_in[33];
  const float* iW1 = (const float*)d_in[34]; const float* ib1 = (const float*)d_in[35];
  const float* iW2 = (const float*)d_in[36]; const float* ib2 = (const float*)d_in[37];
  const float* ig  = (const float*)d_in[38]; const float* ibe = (const float*)d_in[39];
  const float* aw  = (const float*)d_in[40];

  char* ws = (char*)d_ws;
  float* H1pre = (float*)ws;          // 12 x 1024
  float* Ys    = H1pre + 12288;       // 12 x 1024
  float* bias1 = Ys + 12288;          // 4 x 1024
  float* mnrv  = bias1 + 4096;        // 4 x 3072 (batch-major, scaled LN outputs)
  unsigned short* W1T  = (unsigned short*)(ws + (1ull << 20));          // 1024x4096 bf16 (8 MiB)
  unsigned short* W2T  = (unsigned short*)(ws + (9ull << 20));          // 1024x1024 bf16 (2 MiB)
  unsigned short* cat4 = (unsigned short*)(ws + (11ull << 20));         // 8192x4096 bf16 (64 MiB)
  unsigned short* Hb   = (unsigned short*)(ws + (75ull << 20));         // 8192x1024 bf16 (16 MiB)
  unsigned short* Yb   = cat4;  // bf16 Y reuses cat4 region (dead after GEMM1)

  // zero H1pre + Ys + bias1 (bias folded into split-K kernels' first slice)
  hipMemsetAsync(ws, 0, (12288 + 12288 + 4096) * sizeof(float), stream);
  state_h1_acc<<<dim3(8, 10), 256, 0, stream>>>(mem, noi, res, mW1, nW1, rW1,
                                                mb1, nb1, rb1, H1pre);
  state_y_acc<<<dim3(8, 16, 3), 256, 0, stream>>>(H1pre, mW2, nW2, rW2,
                                                  mb2, nb2, rb2, Ys);
  state_ln<<<12, 256, 0, stream>>>(Ys, mg, mbe, ng, nbe, rg, rbe, aw, mnrv);
  prep_all<<<8192 + 4096 + 1024 + 384, 256, 0, stream>>>(
      x, pid, cid, tms, sct, pwg, pwb, cpg, cpb, tmg, tmb, msg, msb,
      iW1, iW2, aw, mnrv, ib1, cat4, W1T, W2T, bias1);
  gemm_bt<1><<<dim3(64, 8), 256, 0, stream>>>(cat4, W1T, bias1, (void*)Hb, 4096);
  gemm_bt<2><<<dim3(64, 8), 256, 0, stream>>>(Hb, W2T, ib2, (void*)Yb, 1024);
  final_ln<<<8192, 256, 0, stream>>>(Yb, ig, ibe, (float*)d_out);
}